// Round 4
// baseline (1277.978 us; speedup 1.0000x reference)
//
#include <hip/hip_runtime.h>
#include <stdint.h>

#define B_ 8
#define L_ 64
#define HID_ 256
#define H_ 8
#define D_ 32
#define INVSQ 0.17677669529663687f
#define NEGINF (-3.0e38f)

// ---------------------------------------------------------------------------
// K1: q,k,v projections + qhat = Wtq^T q, khat = Wtk^T k, betaq = btq.q, betak = btk.k
// grid (B, L/4), 256 threads. thread t owns output feature t for 4 l's.
// ---------------------------------------------------------------------------
__global__ __launch_bounds__(256) void k_qkv(
    const float* __restrict__ x,
    const float* __restrict__ Wq, const float* __restrict__ bq,
    const float* __restrict__ Wk, const float* __restrict__ bk,
    const float* __restrict__ Wv, const float* __restrict__ bv,
    const float* __restrict__ Wtq, const float* __restrict__ btq,
    const float* __restrict__ Wtk, const float* __restrict__ btk,
    float* __restrict__ q, float* __restrict__ k, float* __restrict__ v,
    float* __restrict__ qh, float* __restrict__ kh,
    float* __restrict__ betaq, float* __restrict__ betak)
{
    const int b = blockIdx.x;
    const int l0 = blockIdx.y * 4;
    const int t = threadIdx.x;
    __shared__ float xs[4][256];
    __shared__ float ps[4][256];
#pragma unroll
    for (int r = 0; r < 4; r++) xs[r][t] = x[(b * L_ + l0 + r) * HID_ + t];
    __syncthreads();
    const int h = t >> 5, d = t & 31;
    for (int m = 0; m < 3; m++) {
        const float* W  = (m == 0) ? Wq : ((m == 1) ? Wk : Wv);
        const float* bb = (m == 0) ? bq : ((m == 1) ? bk : bv);
        float* o        = (m == 0) ? q  : ((m == 1) ? k  : v);
        float bias = bb[t];
        float a0 = bias, a1 = bias, a2 = bias, a3 = bias;
        const float* Wr = W + t * HID_;
        for (int c = 0; c < HID_; c += 4) {
            float4 wp = *(const float4*)(Wr + c);
            float4 x0 = *(const float4*)&xs[0][c];
            float4 x1 = *(const float4*)&xs[1][c];
            float4 x2 = *(const float4*)&xs[2][c];
            float4 x3 = *(const float4*)&xs[3][c];
            a0 += x0.x * wp.x + x0.y * wp.y + x0.z * wp.z + x0.w * wp.w;
            a1 += x1.x * wp.x + x1.y * wp.y + x1.z * wp.z + x1.w * wp.w;
            a2 += x2.x * wp.x + x2.y * wp.y + x2.z * wp.z + x2.w * wp.w;
            a3 += x3.x * wp.x + x3.y * wp.y + x3.z * wp.z + x3.w * wp.w;
        }
        const int ob = (b * H_ + h) * L_;
        o[(ob + l0 + 0) * D_ + d] = a0;
        o[(ob + l0 + 1) * D_ + d] = a1;
        o[(ob + l0 + 2) * D_ + d] = a2;
        o[(ob + l0 + 3) * D_ + d] = a3;
        if (m < 2) {
            __syncthreads();
            ps[0][t] = a0; ps[1][t] = a1; ps[2][t] = a2; ps[3][t] = a3;
            __syncthreads();
            const float* Wt = (m == 0) ? Wtq : Wtk;
            const float* bt = (m == 0) ? btq : btk;
            float* oh = (m == 0) ? qh : kh;
            float h0 = 0.f, h1 = 0.f, h2 = 0.f, h3 = 0.f;
            for (int dd = 0; dd < D_; dd++) {
                float wv = Wt[dd * D_ + d];  // qh[e=d] = sum_dd q[dd] * Wtq[dd][d]
                h0 += ps[0][h * D_ + dd] * wv;
                h1 += ps[1][h * D_ + dd] * wv;
                h2 += ps[2][h * D_ + dd] * wv;
                h3 += ps[3][h * D_ + dd] * wv;
            }
            oh[(ob + l0 + 0) * D_ + d] = h0;
            oh[(ob + l0 + 1) * D_ + d] = h1;
            oh[(ob + l0 + 2) * D_ + d] = h2;
            oh[(ob + l0 + 3) * D_ + d] = h3;
            if (d == 0) {
                float* obeta = (m == 0) ? betaq : betak;
                for (int r = 0; r < 4; r++) {
                    float s2 = 0.f;
                    for (int dd = 0; dd < D_; dd++) s2 += bt[dd] * ps[r][h * D_ + dd];
                    obeta[ob + l0 + r] = s2;
                }
            }
            __syncthreads();
        }
    }
}

// ---------------------------------------------------------------------------
// K2: sq/sv = structure @ [Wsq;Wsv]^T + bias.  grid 512 = (b,i), 256 threads,
// 64x64 tile (j x out), K=256 in 4 chunks of 64 staged in LDS.
// ---------------------------------------------------------------------------
__global__ __launch_bounds__(256) void k_struct(
    const float* __restrict__ S,
    const float* __restrict__ Wsq, const float* __restrict__ bsq,
    const float* __restrict__ Wsv, const float* __restrict__ bsv,
    float* __restrict__ sq, float* __restrict__ sv)
{
    const int bid = blockIdx.x;
    const int b = bid >> 6, i = bid & 63;
    const int t = threadIdx.x;
    __shared__ float xs[64][68];
    __shared__ float ws[64][64];
    const int j0 = (t >> 4) << 2, o0 = (t & 15) << 2;
    float acc[4][4];
#pragma unroll
    for (int a = 0; a < 4; a++)
#pragma unroll
        for (int bb2 = 0; bb2 < 4; bb2++) acc[a][bb2] = 0.f;

    for (int cc = 0; cc < 4; cc++) {
        __syncthreads();
        const int cbase = cc * 64;
#pragma unroll
        for (int r = 0; r < 16; r++) {
            int idx = r * 256 + t;
            int j = idx >> 6, c = idx & 63;
            xs[j][c] = S[((b * 64 + i) * 64 + j) * 256 + cbase + c];
        }
#pragma unroll
        for (int r = 0; r < 16; r++) {
            int idx = r * 256 + t;
            int o = idx & 63, c = idx >> 6;
            const float* Wm = (o < 32) ? Wsq : Wsv;
            int oo = o & 31;
            ws[c][o] = Wm[oo * 256 + cbase + c];
        }
        __syncthreads();
        for (int c = 0; c < 64; c += 4) {
            float4 xv0 = *(const float4*)&xs[j0 + 0][c];
            float4 xv1 = *(const float4*)&xs[j0 + 1][c];
            float4 xv2 = *(const float4*)&xs[j0 + 2][c];
            float4 xv3 = *(const float4*)&xs[j0 + 3][c];
#define KSTEP(XC0, XC1, XC2, XC3, CI) { \
    float4 wv = *(const float4*)&ws[c + CI][o0]; \
    acc[0][0] += XC0 * wv.x; acc[0][1] += XC0 * wv.y; acc[0][2] += XC0 * wv.z; acc[0][3] += XC0 * wv.w; \
    acc[1][0] += XC1 * wv.x; acc[1][1] += XC1 * wv.y; acc[1][2] += XC1 * wv.z; acc[1][3] += XC1 * wv.w; \
    acc[2][0] += XC2 * wv.x; acc[2][1] += XC2 * wv.y; acc[2][2] += XC2 * wv.z; acc[2][3] += XC2 * wv.w; \
    acc[3][0] += XC3 * wv.x; acc[3][1] += XC3 * wv.y; acc[3][2] += XC3 * wv.z; acc[3][3] += XC3 * wv.w; }
            KSTEP(xv0.x, xv1.x, xv2.x, xv3.x, 0)
            KSTEP(xv0.y, xv1.y, xv2.y, xv3.y, 1)
            KSTEP(xv0.z, xv1.z, xv2.z, xv3.z, 2)
            KSTEP(xv0.w, xv1.w, xv2.w, xv3.w, 3)
#undef KSTEP
        }
    }
#pragma unroll
    for (int oo = 0; oo < 4; oo++) {
        int o = o0 + oo;
        float bias = (o < 32) ? bsq[o] : bsv[o - 32];
#pragma unroll
        for (int jj = 0; jj < 4; jj++) {
            int j = j0 + jj;
            float val = acc[jj][oo] + bias;
            int base = ((b * 64 + i) * 64 + j) * 32;
            if (o < 32) sq[base + o] = val;
            else        sv[base + o - 32] = val;
        }
    }
}

// ---------------------------------------------------------------------------
// K3: sqhat = Wtq^T sq (contract over first index), bsq_ = btq.sq
// ---------------------------------------------------------------------------
__global__ __launch_bounds__(256) void k_shat(
    const float* __restrict__ sq, const float* __restrict__ Wtq, const float* __restrict__ btq,
    float* __restrict__ sqh, float* __restrict__ bsq_)
{
    int gid = blockIdx.x * 256 + threadIdx.x;
    int site = gid >> 5, e = gid & 31;
    const float* row = sq + site * 32;
    float a = 0.f;
#pragma unroll
    for (int dd = 0; dd < 32; dd++) a += row[dd] * Wtq[dd * 32 + e];
    sqh[site * 32 + e] = a;
    if (e == 0) {
        float s2 = 0.f;
#pragma unroll
        for (int dd = 0; dd < 32; dd++) s2 += row[dd] * btq[dd];
        bsq_[site] = s2;
    }
}

// ---------------------------------------------------------------------------
// K4: main flash kernel. grid 512 = (b,i). 4 waves; wave w handles h=2w,2w+1;
// lane = k. Online softmax over j (64 per block); partials (m,l,acc) per i.
// score = (q5.k + T.(q5hat + khat) + bq5 + bk) * invsq + mi*mj*mk
// ---------------------------------------------------------------------------
__global__ __launch_bounds__(256, 2) void k_main(
    const float* __restrict__ triple, const float* __restrict__ mask,
    const float* __restrict__ q, const float* __restrict__ k, const float* __restrict__ v,
    const float* __restrict__ qh, const float* __restrict__ kh,
    const float* __restrict__ betaq, const float* __restrict__ betak,
    const float* __restrict__ sq, const float* __restrict__ sv,
    const float* __restrict__ sqh, const float* __restrict__ bsq_,
    float* __restrict__ Pm, float* __restrict__ Pl, float* __restrict__ Pacc)
{
    const int bid = blockIdx.x;
    const int b = bid >> 6, i = bid & 63;
    const int t = threadIdx.x;
    const int w = t >> 6, lane = t & 63;
    __shared__ float q5t[8][8][32];
    __shared__ float qh5t[8][8][32];
    __shared__ float v5t[8][8][32];
    __shared__ float bq5t[8][8];
    __shared__ float mjs[8];

    float kk0[32], kk1[32], kh0[32], kh1[32];
    {
        const float* p0 = k  + ((b * H_ + 2 * w) * L_ + lane) * D_;
        const float* p1 = k  + ((b * H_ + 2 * w + 1) * L_ + lane) * D_;
        const float* p2 = kh + ((b * H_ + 2 * w) * L_ + lane) * D_;
        const float* p3 = kh + ((b * H_ + 2 * w + 1) * L_ + lane) * D_;
#pragma unroll
        for (int c = 0; c < 8; c++) {
            float4 a;
            a = *(const float4*)(p0 + 4 * c); kk0[4*c]=a.x; kk0[4*c+1]=a.y; kk0[4*c+2]=a.z; kk0[4*c+3]=a.w;
            a = *(const float4*)(p1 + 4 * c); kk1[4*c]=a.x; kk1[4*c+1]=a.y; kk1[4*c+2]=a.z; kk1[4*c+3]=a.w;
            a = *(const float4*)(p2 + 4 * c); kh0[4*c]=a.x; kh0[4*c+1]=a.y; kh0[4*c+2]=a.z; kh0[4*c+3]=a.w;
            a = *(const float4*)(p3 + 4 * c); kh1[4*c]=a.x; kh1[4*c+1]=a.y; kh1[4*c+2]=a.z; kh1[4*c+3]=a.w;
        }
    }
    const float bk0 = betak[(b * H_ + 2 * w) * L_ + lane];
    const float bk1 = betak[(b * H_ + 2 * w + 1) * L_ + lane];
    const float mk = mask[b * L_ + lane];
    const float mi = mask[b * L_ + i];
    float m_0 = NEGINF, m_1 = NEGINF, l_0 = 0.f, l_1 = 0.f;
    float acc0[32], acc1[32];
#pragma unroll
    for (int c = 0; c < 32; c++) { acc0[c] = 0.f; acc1[c] = 0.f; }

    for (int j0 = 0; j0 < 64; j0 += 8) {
        __syncthreads();
#pragma unroll
        for (int r = 0; r < 2; r++) {
            int idx = r * 256 + t;             // 0..511 -> (jl, hh, dq)
            int jl = idx >> 6, rem = idx & 63, hh = rem >> 3, dq = rem & 7;
            int jg = j0 + jl;
            const int qrow_i = ((b * H_ + hh) * L_ + i) * D_ + dq * 4;
            const int qrow_j = ((b * H_ + hh) * L_ + jg) * D_ + dq * 4;
            const int srow   = ((b * L_ + i) * L_ + jg) * D_ + dq * 4;
            float4 A, Bv, C;
            A = *(const float4*)(q + qrow_i); Bv = *(const float4*)(q + qrow_j); C = *(const float4*)(sq + srow);
            *(float4*)&q5t[jl][hh][dq * 4]  = make_float4(A.x+Bv.x+C.x, A.y+Bv.y+C.y, A.z+Bv.z+C.z, A.w+Bv.w+C.w);
            A = *(const float4*)(qh + qrow_i); Bv = *(const float4*)(qh + qrow_j); C = *(const float4*)(sqh + srow);
            *(float4*)&qh5t[jl][hh][dq * 4] = make_float4(A.x+Bv.x+C.x, A.y+Bv.y+C.y, A.z+Bv.z+C.z, A.w+Bv.w+C.w);
            A = *(const float4*)(v + qrow_i); Bv = *(const float4*)(v + qrow_j); C = *(const float4*)(sv + srow);
            *(float4*)&v5t[jl][hh][dq * 4]  = make_float4(A.x+Bv.x+C.x, A.y+Bv.y+C.y, A.z+Bv.z+C.z, A.w+Bv.w+C.w);
        }
        if (t < 64) {
            int jl = t >> 3, hh = t & 7;
            int jg = j0 + jl;
            bq5t[jl][hh] = betaq[(b * H_ + hh) * L_ + i] + betaq[(b * H_ + hh) * L_ + jg]
                         + bsq_[(b * L_ + i) * L_ + jg];
        }
        if (t < 8) mjs[t] = mask[b * L_ + j0 + t];
        __syncthreads();
        for (int jl = 0; jl < 8; jl++) {
            const int jg = j0 + jl;
            const float4* tp = (const float4*)(triple + (size_t)(((b * L_ + i) * L_ + jg) * L_ + lane) * D_);
            float4 Tv[8];
#pragma unroll
            for (int c = 0; c < 8; c++) Tv[c] = tp[c];
            const float mbase = mi * mjs[jl] * mk;
#define DO_H(HH, KK, KH, MRUN, LRUN, ACC, BKS) { \
    const int h_ = 2 * w + HH; \
    float s = bq5t[jl][h_] + BKS; \
    const float4* A4 = (const float4*)&q5t[jl][h_][0]; \
    const float4* B4 = (const float4*)&qh5t[jl][h_][0]; \
    _Pragma("unroll") \
    for (int c = 0; c < 8; c++) { \
        float4 A = A4[c]; float4 Bq = B4[c]; float4 Tt = Tv[c]; \
        s += A.x * KK[4*c] + A.y * KK[4*c+1] + A.z * KK[4*c+2] + A.w * KK[4*c+3]; \
        s += (Bq.x + KH[4*c]) * Tt.x + (Bq.y + KH[4*c+1]) * Tt.y \
           + (Bq.z + KH[4*c+2]) * Tt.z + (Bq.w + KH[4*c+3]) * Tt.w; \
    } \
    s = s * INVSQ + mbase; \
    if (s > MRUN) { \
        float sc = __expf(MRUN - s); MRUN = s; LRUN *= sc; \
        _Pragma("unroll") \
        for (int c2 = 0; c2 < 32; c2++) ACC[c2] *= sc; \
    } \
    float e = __expf(s - MRUN); LRUN += e; \
    const float4* V4 = (const float4*)&v5t[jl][h_][0]; \
    _Pragma("unroll") \
    for (int c = 0; c < 8; c++) { \
        float4 V = V4[c]; \
        ACC[4*c] += e * V.x; ACC[4*c+1] += e * V.y; ACC[4*c+2] += e * V.z; ACC[4*c+3] += e * V.w; \
    } }
            DO_H(0, kk0, kh0, m_0, l_0, acc0, bk0)
            DO_H(1, kk1, kh1, m_1, l_1, acc1, bk1)
#undef DO_H
        }
    }
    {
        const int base0 = ((b * L_ + i) * H_ + 2 * w) * L_ + lane;
        const int base1 = base0 + L_;
        Pm[base0] = m_0; Pm[base1] = m_1;
        Pl[base0] = l_0; Pl[base1] = l_1;
        float* pa0 = Pacc + (size_t)base0 * 32;
        float* pa1 = Pacc + (size_t)base1 * 32;
#pragma unroll
        for (int c = 0; c < 8; c++) {
            *(float4*)(pa0 + 4 * c) = make_float4(acc0[4*c], acc0[4*c+1], acc0[4*c+2], acc0[4*c+3]);
            *(float4*)(pa1 + 4 * c) = make_float4(acc1[4*c], acc1[4*c+1], acc1[4*c+2], acc1[4*c+3]);
        }
    }
}

// ---------------------------------------------------------------------------
// K5: merge 64 i-partials per (b,h,k); write f32 output [b, k, h*32+d]
// ---------------------------------------------------------------------------
__global__ __launch_bounds__(256) void k_merge(
    const float* __restrict__ Pm, const float* __restrict__ Pl, const float* __restrict__ Pacc,
    float* __restrict__ out)
{
    const int bid = blockIdx.x;
    const int b = bid >> 6;
    const int rest = bid & 63;
    const int h = rest >> 3;
    const int k0 = (rest & 7) * 8;
    const int t = threadIdx.x;
    const int s = t >> 5, d = t & 31;
    const int kq = k0 + s;
    float M = NEGINF;
    for (int i2 = 0; i2 < 64; i2++)
        M = fmaxf(M, Pm[((b * 64 + i2) * 8 + h) * 64 + kq]);
    float Ls = 0.f, ctx = 0.f;
    for (int i2 = 0; i2 < 64; i2++) {
        int idx = ((b * 64 + i2) * 8 + h) * 64 + kq;
        float wgt = __expf(Pm[idx] - M);
        Ls += Pl[idx] * wgt;
        ctx += wgt * Pacc[(size_t)idx * 32 + d];
    }
    out[(b * 64 + kq) * 256 + h * 32 + d] = ctx / Ls;
}

// ---------------------------------------------------------------------------
// workspace layout (floats) — FIXED round 4: sq/sv/sqh are B*L*L*D = 1048576
// floats (4 MB) each; previous table allocated 524288 (2 MB) and overlapped.
// ---------------------------------------------------------------------------
#define OFF_Q    0          //  131072  (B*H*L*D)
#define OFF_K    131072     //  131072
#define OFF_V    262144     //  131072
#define OFF_QH   393216     //  131072
#define OFF_KH   524288     //  131072
#define OFF_BQ   655360     //    4096  (B*H*L)
#define OFF_BK   659456     //    4096
#define OFF_SQ   663552     // 1048576  (B*L*L*D)
#define OFF_SV   1712128    // 1048576
#define OFF_SQH  2760704    // 1048576
#define OFF_BSQ  3809280    //   32768  (B*L*L)
#define OFF_PM   3842048    //  262144  (B*L*H*L)
#define OFF_PL   4104192    //  262144
#define OFF_PACC 4366336    // 8388608  (B*L*H*L*D)
// end = 12754944 floats = 51.0 MB

extern "C" void kernel_launch(void* const* d_in, const int* in_sizes, int n_in,
                              void* d_out, int out_size, void* d_ws, size_t ws_size,
                              hipStream_t stream)
{
    (void)in_sizes; (void)n_in; (void)out_size; (void)ws_size;
    const float* x    = (const float*)d_in[0];
    const float* mask = (const float*)d_in[1];
    const float* S    = (const float*)d_in[2];
    const float* T    = (const float*)d_in[3];
    const float* Wq   = (const float*)d_in[4];  const float* bq  = (const float*)d_in[5];
    const float* Wk   = (const float*)d_in[6];  const float* bk  = (const float*)d_in[7];
    const float* Wv   = (const float*)d_in[8];  const float* bv  = (const float*)d_in[9];
    const float* Wsq  = (const float*)d_in[10]; const float* bsq = (const float*)d_in[11];
    const float* Wsv  = (const float*)d_in[12]; const float* bsv = (const float*)d_in[13];
    const float* Wtq  = (const float*)d_in[14]; const float* btq = (const float*)d_in[15];
    const float* Wtk  = (const float*)d_in[16]; const float* btk = (const float*)d_in[17];
    float* out = (float*)d_out;
    float* ws = (float*)d_ws;

    float* q    = ws + OFF_Q;   float* k    = ws + OFF_K;   float* v   = ws + OFF_V;
    float* qh   = ws + OFF_QH;  float* kh   = ws + OFF_KH;
    float* bQ   = ws + OFF_BQ;  float* bK   = ws + OFF_BK;
    float* sq   = ws + OFF_SQ;  float* sv   = ws + OFF_SV;
    float* sqh  = ws + OFF_SQH; float* bSQ  = ws + OFF_BSQ;
    float* Pm   = ws + OFF_PM;  float* Pl   = ws + OFF_PL;  float* Pacc = ws + OFF_PACC;

    k_qkv  <<<dim3(8, 16), 256, 0, stream>>>(x, Wq, bq, Wk, bk, Wv, bv, Wtq, btq, Wtk, btk,
                                             q, k, v, qh, kh, bQ, bK);
    k_struct<<<512, 256, 0, stream>>>(S, Wsq, bsq, Wsv, bsv, sq, sv);
    k_shat <<<4096, 256, 0, stream>>>(sq, Wtq, btq, sqh, bSQ);
    k_main <<<512, 256, 0, stream>>>(T, mask, q, k, v, qh, kh, bQ, bK, sq, sv, sqh, bSQ,
                                     Pm, Pl, Pacc);
    k_merge<<<512, 256, 0, stream>>>(Pm, Pl, Pacc, out);
}

// Round 5
// 708.032 us; speedup vs baseline: 1.8050x; 1.8050x over previous
//
#include <hip/hip_runtime.h>
#include <stdint.h>

#define B_ 8
#define L_ 64
#define HID_ 256
#define H_ 8
#define D_ 32
#define INVSQ 0.17677669529663687f
#define NEGINF (-3.0e38f)

// ---------------------------------------------------------------------------
// K1: q,k,v projections + qhat = Wtq^T q, khat = Wtk^T k, betaq = btq.q, betak = btk.k
// ---------------------------------------------------------------------------
__global__ __launch_bounds__(256) void k_qkv(
    const float* __restrict__ x,
    const float* __restrict__ Wq, const float* __restrict__ bq,
    const float* __restrict__ Wk, const float* __restrict__ bk,
    const float* __restrict__ Wv, const float* __restrict__ bv,
    const float* __restrict__ Wtq, const float* __restrict__ btq,
    const float* __restrict__ Wtk, const float* __restrict__ btk,
    float* __restrict__ q, float* __restrict__ k, float* __restrict__ v,
    float* __restrict__ qh, float* __restrict__ kh,
    float* __restrict__ betaq, float* __restrict__ betak)
{
    const int b = blockIdx.x;
    const int l0 = blockIdx.y * 4;
    const int t = threadIdx.x;
    __shared__ float xs[4][256];
    __shared__ float ps[4][256];
#pragma unroll
    for (int r = 0; r < 4; r++) xs[r][t] = x[(b * L_ + l0 + r) * HID_ + t];
    __syncthreads();
    const int h = t >> 5, d = t & 31;
    for (int m = 0; m < 3; m++) {
        const float* W  = (m == 0) ? Wq : ((m == 1) ? Wk : Wv);
        const float* bb = (m == 0) ? bq : ((m == 1) ? bk : bv);
        float* o        = (m == 0) ? q  : ((m == 1) ? k  : v);
        float bias = bb[t];
        float a0 = bias, a1 = bias, a2 = bias, a3 = bias;
        const float* Wr = W + t * HID_;
        for (int c = 0; c < HID_; c += 4) {
            float4 wp = *(const float4*)(Wr + c);
            float4 x0 = *(const float4*)&xs[0][c];
            float4 x1 = *(const float4*)&xs[1][c];
            float4 x2 = *(const float4*)&xs[2][c];
            float4 x3 = *(const float4*)&xs[3][c];
            a0 += x0.x * wp.x + x0.y * wp.y + x0.z * wp.z + x0.w * wp.w;
            a1 += x1.x * wp.x + x1.y * wp.y + x1.z * wp.z + x1.w * wp.w;
            a2 += x2.x * wp.x + x2.y * wp.y + x2.z * wp.z + x2.w * wp.w;
            a3 += x3.x * wp.x + x3.y * wp.y + x3.z * wp.z + x3.w * wp.w;
        }
        const int ob = (b * H_ + h) * L_;
        o[(ob + l0 + 0) * D_ + d] = a0;
        o[(ob + l0 + 1) * D_ + d] = a1;
        o[(ob + l0 + 2) * D_ + d] = a2;
        o[(ob + l0 + 3) * D_ + d] = a3;
        if (m < 2) {
            __syncthreads();
            ps[0][t] = a0; ps[1][t] = a1; ps[2][t] = a2; ps[3][t] = a3;
            __syncthreads();
            const float* Wt = (m == 0) ? Wtq : Wtk;
            const float* bt = (m == 0) ? btq : btk;
            float* oh = (m == 0) ? qh : kh;
            float h0 = 0.f, h1 = 0.f, h2 = 0.f, h3 = 0.f;
            for (int dd = 0; dd < D_; dd++) {
                float wv = Wt[dd * D_ + d];
                h0 += ps[0][h * D_ + dd] * wv;
                h1 += ps[1][h * D_ + dd] * wv;
                h2 += ps[2][h * D_ + dd] * wv;
                h3 += ps[3][h * D_ + dd] * wv;
            }
            oh[(ob + l0 + 0) * D_ + d] = h0;
            oh[(ob + l0 + 1) * D_ + d] = h1;
            oh[(ob + l0 + 2) * D_ + d] = h2;
            oh[(ob + l0 + 3) * D_ + d] = h3;
            if (d == 0) {
                float* obeta = (m == 0) ? betaq : betak;
                for (int r = 0; r < 4; r++) {
                    float s2 = 0.f;
                    for (int dd = 0; dd < D_; dd++) s2 += bt[dd] * ps[r][h * D_ + dd];
                    obeta[ob + l0 + r] = s2;
                }
            }
            __syncthreads();
        }
    }
}

// ---------------------------------------------------------------------------
// K2: sq/sv = structure @ [Wsq;Wsv]^T + bias.
// ---------------------------------------------------------------------------
__global__ __launch_bounds__(256) void k_struct(
    const float* __restrict__ S,
    const float* __restrict__ Wsq, const float* __restrict__ bsq,
    const float* __restrict__ Wsv, const float* __restrict__ bsv,
    float* __restrict__ sq, float* __restrict__ sv)
{
    const int bid = blockIdx.x;
    const int b = bid >> 6, i = bid & 63;
    const int t = threadIdx.x;
    __shared__ float xs[64][68];
    __shared__ float ws[64][64];
    const int j0 = (t >> 4) << 2, o0 = (t & 15) << 2;
    float acc[4][4];
#pragma unroll
    for (int a = 0; a < 4; a++)
#pragma unroll
        for (int bb2 = 0; bb2 < 4; bb2++) acc[a][bb2] = 0.f;

    for (int cc = 0; cc < 4; cc++) {
        __syncthreads();
        const int cbase = cc * 64;
#pragma unroll
        for (int r = 0; r < 16; r++) {
            int idx = r * 256 + t;
            int j = idx >> 6, c = idx & 63;
            xs[j][c] = S[((b * 64 + i) * 64 + j) * 256 + cbase + c];
        }
#pragma unroll
        for (int r = 0; r < 16; r++) {
            int idx = r * 256 + t;
            int o = idx & 63, c = idx >> 6;
            const float* Wm = (o < 32) ? Wsq : Wsv;
            int oo = o & 31;
            ws[c][o] = Wm[oo * 256 + cbase + c];
        }
        __syncthreads();
        for (int c = 0; c < 64; c += 4) {
            float4 xv0 = *(const float4*)&xs[j0 + 0][c];
            float4 xv1 = *(const float4*)&xs[j0 + 1][c];
            float4 xv2 = *(const float4*)&xs[j0 + 2][c];
            float4 xv3 = *(const float4*)&xs[j0 + 3][c];
#define KSTEP(XC0, XC1, XC2, XC3, CI) { \
    float4 wv = *(const float4*)&ws[c + CI][o0]; \
    acc[0][0] += XC0 * wv.x; acc[0][1] += XC0 * wv.y; acc[0][2] += XC0 * wv.z; acc[0][3] += XC0 * wv.w; \
    acc[1][0] += XC1 * wv.x; acc[1][1] += XC1 * wv.y; acc[1][2] += XC1 * wv.z; acc[1][3] += XC1 * wv.w; \
    acc[2][0] += XC2 * wv.x; acc[2][1] += XC2 * wv.y; acc[2][2] += XC2 * wv.z; acc[2][3] += XC2 * wv.w; \
    acc[3][0] += XC3 * wv.x; acc[3][1] += XC3 * wv.y; acc[3][2] += XC3 * wv.z; acc[3][3] += XC3 * wv.w; }
            KSTEP(xv0.x, xv1.x, xv2.x, xv3.x, 0)
            KSTEP(xv0.y, xv1.y, xv2.y, xv3.y, 1)
            KSTEP(xv0.z, xv1.z, xv2.z, xv3.z, 2)
            KSTEP(xv0.w, xv1.w, xv2.w, xv3.w, 3)
#undef KSTEP
        }
    }
#pragma unroll
    for (int oo = 0; oo < 4; oo++) {
        int o = o0 + oo;
        float bias = (o < 32) ? bsq[o] : bsv[o - 32];
#pragma unroll
        for (int jj = 0; jj < 4; jj++) {
            int j = j0 + jj;
            float val = acc[jj][oo] + bias;
            int base = ((b * 64 + i) * 64 + j) * 32;
            if (o < 32) sq[base + o] = val;
            else        sv[base + o - 32] = val;
        }
    }
}

// ---------------------------------------------------------------------------
// K3: sqhat = Wtq^T sq (contract over first index), bsq_ = btq.sq
// ---------------------------------------------------------------------------
__global__ __launch_bounds__(256) void k_shat(
    const float* __restrict__ sq, const float* __restrict__ Wtq, const float* __restrict__ btq,
    float* __restrict__ sqh, float* __restrict__ bsq_)
{
    int gid = blockIdx.x * 256 + threadIdx.x;
    int site = gid >> 5, e = gid & 31;
    const float* row = sq + site * 32;
    float a = 0.f;
#pragma unroll
    for (int dd = 0; dd < 32; dd++) a += row[dd] * Wtq[dd * 32 + e];
    sqh[site * 32 + e] = a;
    if (e == 0) {
        float s2 = 0.f;
#pragma unroll
        for (int dd = 0; dd < 32; dd++) s2 += row[dd] * btq[dd];
        bsq_[site] = s2;
    }
}

// ---------------------------------------------------------------------------
// K4: main flash kernel. grid 512 = (b,i). 4 waves; wave w handles h=2w,2w+1;
// lane = k. Fused 2-head inner loop: each T float4 loaded ONCE.
// NOTE: no min-waves clamp — round-4's (256,2) capped VGPR at 128 and spilled
// ~100 floats/thread to scratch (1.5 GB HBM R + 1.5 GB W, VALUBusy 9.5%).
// ---------------------------------------------------------------------------
__global__ __launch_bounds__(256) void k_main(
    const float* __restrict__ triple, const float* __restrict__ mask,
    const float* __restrict__ q, const float* __restrict__ k, const float* __restrict__ v,
    const float* __restrict__ qh, const float* __restrict__ kh,
    const float* __restrict__ betaq, const float* __restrict__ betak,
    const float* __restrict__ sq, const float* __restrict__ sv,
    const float* __restrict__ sqh, const float* __restrict__ bsq_,
    float* __restrict__ Pm, float* __restrict__ Pl, float* __restrict__ Pacc)
{
    const int bid = blockIdx.x;
    const int b = bid >> 6, i = bid & 63;
    const int t = threadIdx.x;
    const int w = t >> 6, lane = t & 63;
    __shared__ float q5t[8][8][32];
    __shared__ float qh5t[8][8][32];
    __shared__ float v5t[8][8][32];
    __shared__ float bq5t[8][8];
    __shared__ float mjs[8];

    float kk0[32], kk1[32], kh0[32], kh1[32];
    {
        const float* p0 = k  + ((b * H_ + 2 * w) * L_ + lane) * D_;
        const float* p1 = k  + ((b * H_ + 2 * w + 1) * L_ + lane) * D_;
        const float* p2 = kh + ((b * H_ + 2 * w) * L_ + lane) * D_;
        const float* p3 = kh + ((b * H_ + 2 * w + 1) * L_ + lane) * D_;
#pragma unroll
        for (int c = 0; c < 8; c++) {
            float4 a;
            a = *(const float4*)(p0 + 4 * c); kk0[4*c]=a.x; kk0[4*c+1]=a.y; kk0[4*c+2]=a.z; kk0[4*c+3]=a.w;
            a = *(const float4*)(p1 + 4 * c); kk1[4*c]=a.x; kk1[4*c+1]=a.y; kk1[4*c+2]=a.z; kk1[4*c+3]=a.w;
            a = *(const float4*)(p2 + 4 * c); kh0[4*c]=a.x; kh0[4*c+1]=a.y; kh0[4*c+2]=a.z; kh0[4*c+3]=a.w;
            a = *(const float4*)(p3 + 4 * c); kh1[4*c]=a.x; kh1[4*c+1]=a.y; kh1[4*c+2]=a.z; kh1[4*c+3]=a.w;
        }
    }
    const float bk0 = betak[(b * H_ + 2 * w) * L_ + lane];
    const float bk1 = betak[(b * H_ + 2 * w + 1) * L_ + lane];
    const float mk = mask[b * L_ + lane];
    const float mi = mask[b * L_ + i];
    float m_0 = NEGINF, m_1 = NEGINF, l_0 = 0.f, l_1 = 0.f;
    float acc0[32], acc1[32];
#pragma unroll
    for (int c = 0; c < 32; c++) { acc0[c] = 0.f; acc1[c] = 0.f; }

    for (int j0 = 0; j0 < 64; j0 += 8) {
        __syncthreads();
#pragma unroll
        for (int r = 0; r < 2; r++) {
            int idx = r * 256 + t;             // 0..511 -> (jl, hh, dq)
            int jl = idx >> 6, rem = idx & 63, hh = rem >> 3, dq = rem & 7;
            int jg = j0 + jl;
            const int qrow_i = ((b * H_ + hh) * L_ + i) * D_ + dq * 4;
            const int qrow_j = ((b * H_ + hh) * L_ + jg) * D_ + dq * 4;
            const int srow   = ((b * L_ + i) * L_ + jg) * D_ + dq * 4;
            float4 A, Bv, C;
            A = *(const float4*)(q + qrow_i); Bv = *(const float4*)(q + qrow_j); C = *(const float4*)(sq + srow);
            *(float4*)&q5t[jl][hh][dq * 4]  = make_float4(A.x+Bv.x+C.x, A.y+Bv.y+C.y, A.z+Bv.z+C.z, A.w+Bv.w+C.w);
            A = *(const float4*)(qh + qrow_i); Bv = *(const float4*)(qh + qrow_j); C = *(const float4*)(sqh + srow);
            *(float4*)&qh5t[jl][hh][dq * 4] = make_float4(A.x+Bv.x+C.x, A.y+Bv.y+C.y, A.z+Bv.z+C.z, A.w+Bv.w+C.w);
            A = *(const float4*)(v + qrow_i); Bv = *(const float4*)(v + qrow_j); C = *(const float4*)(sv + srow);
            *(float4*)&v5t[jl][hh][dq * 4]  = make_float4(A.x+Bv.x+C.x, A.y+Bv.y+C.y, A.z+Bv.z+C.z, A.w+Bv.w+C.w);
        }
        if (t < 64) {
            int jl = t >> 3, hh = t & 7;
            int jg = j0 + jl;
            bq5t[jl][hh] = betaq[(b * H_ + hh) * L_ + i] + betaq[(b * H_ + hh) * L_ + jg]
                         + bsq_[(b * L_ + i) * L_ + jg];
        }
        if (t < 8) mjs[t] = mask[b * L_ + j0 + t];
        __syncthreads();
        for (int jl = 0; jl < 8; jl++) {
            const int jg = j0 + jl;
            const float4* tp = (const float4*)(triple + (size_t)(((b * L_ + i) * L_ + jg) * L_ + lane) * D_);
            const float mbase = mi * mjs[jl] * mk;
            const int ha = 2 * w, hb = 2 * w + 1;
            float s0 = bq5t[jl][ha] + bk0;
            float s1 = bq5t[jl][hb] + bk1;
            const float4* A0 = (const float4*)&q5t[jl][ha][0];
            const float4* B0 = (const float4*)&qh5t[jl][ha][0];
            const float4* A1 = (const float4*)&q5t[jl][hb][0];
            const float4* B1 = (const float4*)&qh5t[jl][hb][0];
#pragma unroll
            for (int c = 0; c < 8; c++) {
                float4 Tt = tp[c];
                float4 a0 = A0[c], b0 = B0[c];
                float4 a1 = A1[c], b1 = B1[c];
                s0 += a0.x * kk0[4*c]   + a0.y * kk0[4*c+1] + a0.z * kk0[4*c+2] + a0.w * kk0[4*c+3];
                s0 += (b0.x + kh0[4*c])   * Tt.x + (b0.y + kh0[4*c+1]) * Tt.y
                    + (b0.z + kh0[4*c+2]) * Tt.z + (b0.w + kh0[4*c+3]) * Tt.w;
                s1 += a1.x * kk1[4*c]   + a1.y * kk1[4*c+1] + a1.z * kk1[4*c+2] + a1.w * kk1[4*c+3];
                s1 += (b1.x + kh1[4*c])   * Tt.x + (b1.y + kh1[4*c+1]) * Tt.y
                    + (b1.z + kh1[4*c+2]) * Tt.z + (b1.w + kh1[4*c+3]) * Tt.w;
            }
            s0 = s0 * INVSQ + mbase;
            s1 = s1 * INVSQ + mbase;
            if (s0 > m_0) {
                float sc = __expf(m_0 - s0); m_0 = s0; l_0 *= sc;
#pragma unroll
                for (int c2 = 0; c2 < 32; c2++) acc0[c2] *= sc;
            }
            {
                float e = __expf(s0 - m_0); l_0 += e;
                const float4* V4 = (const float4*)&v5t[jl][ha][0];
#pragma unroll
                for (int c = 0; c < 8; c++) {
                    float4 V = V4[c];
                    acc0[4*c] += e * V.x; acc0[4*c+1] += e * V.y;
                    acc0[4*c+2] += e * V.z; acc0[4*c+3] += e * V.w;
                }
            }
            if (s1 > m_1) {
                float sc = __expf(m_1 - s1); m_1 = s1; l_1 *= sc;
#pragma unroll
                for (int c2 = 0; c2 < 32; c2++) acc1[c2] *= sc;
            }
            {
                float e = __expf(s1 - m_1); l_1 += e;
                const float4* V4 = (const float4*)&v5t[jl][hb][0];
#pragma unroll
                for (int c = 0; c < 8; c++) {
                    float4 V = V4[c];
                    acc1[4*c] += e * V.x; acc1[4*c+1] += e * V.y;
                    acc1[4*c+2] += e * V.z; acc1[4*c+3] += e * V.w;
                }
            }
        }
    }
    {
        const int base0 = ((b * L_ + i) * H_ + 2 * w) * L_ + lane;
        const int base1 = base0 + L_;
        Pm[base0] = m_0; Pm[base1] = m_1;
        Pl[base0] = l_0; Pl[base1] = l_1;
        float* pa0 = Pacc + (size_t)base0 * 32;
        float* pa1 = Pacc + (size_t)base1 * 32;
#pragma unroll
        for (int c = 0; c < 8; c++) {
            *(float4*)(pa0 + 4 * c) = make_float4(acc0[4*c], acc0[4*c+1], acc0[4*c+2], acc0[4*c+3]);
            *(float4*)(pa1 + 4 * c) = make_float4(acc1[4*c], acc1[4*c+1], acc1[4*c+2], acc1[4*c+3]);
        }
    }
}

// ---------------------------------------------------------------------------
// K5: merge 64 i-partials per (b,h,k); write f32 output [b, k, h*32+d]
// ---------------------------------------------------------------------------
__global__ __launch_bounds__(256) void k_merge(
    const float* __restrict__ Pm, const float* __restrict__ Pl, const float* __restrict__ Pacc,
    float* __restrict__ out)
{
    const int bid = blockIdx.x;
    const int b = bid >> 6;
    const int rest = bid & 63;
    const int h = rest >> 3;
    const int k0 = (rest & 7) * 8;
    const int t = threadIdx.x;
    const int s = t >> 5, d = t & 31;
    const int kq = k0 + s;
    float M = NEGINF;
    for (int i2 = 0; i2 < 64; i2++)
        M = fmaxf(M, Pm[((b * 64 + i2) * 8 + h) * 64 + kq]);
    float Ls = 0.f, ctx = 0.f;
    for (int i2 = 0; i2 < 64; i2++) {
        int idx = ((b * 64 + i2) * 8 + h) * 64 + kq;
        float wgt = __expf(Pm[idx] - M);
        Ls += Pl[idx] * wgt;
        ctx += wgt * Pacc[(size_t)idx * 32 + d];
    }
    out[(b * 64 + kq) * 256 + h * 32 + d] = ctx / Ls;
}

// ---------------------------------------------------------------------------
// workspace layout (floats) — non-overlapping (fixed round 4)
// ---------------------------------------------------------------------------
#define OFF_Q    0          //  131072  (B*H*L*D)
#define OFF_K    131072     //  131072
#define OFF_V    262144     //  131072
#define OFF_QH   393216     //  131072
#define OFF_KH   524288     //  131072
#define OFF_BQ   655360     //    4096  (B*H*L)
#define OFF_BK   659456     //    4096
#define OFF_SQ   663552     // 1048576  (B*L*L*D)
#define OFF_SV   1712128    // 1048576
#define OFF_SQH  2760704    // 1048576
#define OFF_BSQ  3809280    //   32768  (B*L*L)
#define OFF_PM   3842048    //  262144  (B*L*H*L)
#define OFF_PL   4104192    //  262144
#define OFF_PACC 4366336    // 8388608  (B*L*H*L*D)
// end = 12754944 floats = 51.0 MB

extern "C" void kernel_launch(void* const* d_in, const int* in_sizes, int n_in,
                              void* d_out, int out_size, void* d_ws, size_t ws_size,
                              hipStream_t stream)
{
    (void)in_sizes; (void)n_in; (void)out_size; (void)ws_size;
    const float* x    = (const float*)d_in[0];
    const float* mask = (const float*)d_in[1];
    const float* S    = (const float*)d_in[2];
    const float* T    = (const float*)d_in[3];
    const float* Wq   = (const float*)d_in[4];  const float* bq  = (const float*)d_in[5];
    const float* Wk   = (const float*)d_in[6];  const float* bk  = (const float*)d_in[7];
    const float* Wv   = (const float*)d_in[8];  const float* bv  = (const float*)d_in[9];
    const float* Wsq  = (const float*)d_in[10]; const float* bsq = (const float*)d_in[11];
    const float* Wsv  = (const float*)d_in[12]; const float* bsv = (const float*)d_in[13];
    const float* Wtq  = (const float*)d_in[14]; const float* btq = (const float*)d_in[15];
    const float* Wtk  = (const float*)d_in[16]; const float* btk = (const float*)d_in[17];
    float* out = (float*)d_out;
    float* ws = (float*)d_ws;

    float* q    = ws + OFF_Q;   float* k    = ws + OFF_K;   float* v   = ws + OFF_V;
    float* qh   = ws + OFF_QH;  float* kh   = ws + OFF_KH;
    float* bQ   = ws + OFF_BQ;  float* bK   = ws + OFF_BK;
    float* sq   = ws + OFF_SQ;  float* sv   = ws + OFF_SV;
    float* sqh  = ws + OFF_SQH; float* bSQ  = ws + OFF_BSQ;
    float* Pm   = ws + OFF_PM;  float* Pl   = ws + OFF_PL;  float* Pacc = ws + OFF_PACC;

    k_qkv  <<<dim3(8, 16), 256, 0, stream>>>(x, Wq, bq, Wk, bk, Wv, bv, Wtq, btq, Wtk, btk,
                                             q, k, v, qh, kh, bQ, bK);
    k_struct<<<512, 256, 0, stream>>>(S, Wsq, bsq, Wsv, bsv, sq, sv);
    k_shat <<<4096, 256, 0, stream>>>(sq, Wtq, btq, sqh, bSQ);
    k_main <<<512, 256, 0, stream>>>(T, mask, q, k, v, qh, kh, bQ, bK, sq, sv, sqh, bSQ,
                                     Pm, Pl, Pacc);
    k_merge<<<512, 256, 0, stream>>>(Pm, Pl, Pacc, out);
}